// Round 1
// 180.826 us; speedup vs baseline: 1.1190x; 1.1190x over previous
//
#include <hip/hip_runtime.h>
#include <hip/hip_fp16.h>

// ---------------------------------------------------------------------------
// BasketballGNN round 19: R18 + node-parallel gather phases.
// Theory: agg kernels are latency/overhead-bound (deg~16 -> ~1-trip edge
// loops, 3-4 shuffle steps + off[] round-trip per node, serialized 4x per
// wave). Remap so a wave processes 4 nodes CONCURRENTLY (16 lanes/node,
// 2 sub-groups of 8 for the 64ch gather; 4 sub-groups of 4 for the 32ch
// final agg). Serial phases 4->1, shuffle steps 3->1 (fused) / 4->2 (agg).
// Bytes moved unchanged; everything else identical to R18 (202.3us).
// ---------------------------------------------------------------------------

#define P3CAP 3200   // >= chunk (3128 for E=800k)
#define P4CAP 8192   // >= max edges per 256-node bucket (mean 4082, +64 sigma)
#define BCAP  8192   // per-bucket region stride in bedge

typedef float vf4 __attribute__((ext_vector_type(4)));

__device__ __forceinline__ int block_scan_incl(int v, int* s, int t) {
    s[t] = v;
    __syncthreads();
#pragma unroll
    for (int d = 1; d < 256; d <<= 1) {
        int a = (t >= d) ? s[t - d] : 0;
        __syncthreads();
        s[t] += a;
        __syncthreads();
    }
    return s[t];
}

__host__ __device__ __forceinline__ int chunk_of(int E) {
    return (((E + 255) / 256) + 3) & ~3;
}

// P3' single-pass: stage packed edges in arrival order while counting, LDS
// counting-sort into bucket-grouped order, atomic run reservation, flush.
__global__ __launch_bounds__(256) void part_sort_reserve_kernel(
    const int* __restrict__ src, const int* __restrict__ dst,
    int* __restrict__ btot, int* __restrict__ bedge, int E, int nbuckets)
{
    __shared__ int lh[256], gb[256], cur[256], s[256];
    __shared__ int stageA[P3CAP];
    __shared__ int stageB[P3CAP];
    const int t = threadIdx.x;

    lh[t] = 0;
    __syncthreads();
    const int chunk = chunk_of(E);
    const int e0 = blockIdx.x * chunk;
    const int e1 = min(E, e0 + chunk);
    {
        int e = e0 + t * 4;
        for (; e + 3 < e1; e += 1024) {
            const int4 d4 = *(const int4*)&dst[e];
            const int4 s4 = *(const int4*)&src[e];
            const int i = e - e0;
            int b;
            b = d4.x >> 8; atomicAdd(&lh[b], 1);
            stageA[i]     = (s4.x & 0xffff) | ((d4.x & 255) << 16) | (b << 24);
            b = d4.y >> 8; atomicAdd(&lh[b], 1);
            stageA[i + 1] = (s4.y & 0xffff) | ((d4.y & 255) << 16) | (b << 24);
            b = d4.z >> 8; atomicAdd(&lh[b], 1);
            stageA[i + 2] = (s4.z & 0xffff) | ((d4.z & 255) << 16) | (b << 24);
            b = d4.w >> 8; atomicAdd(&lh[b], 1);
            stageA[i + 3] = (s4.w & 0xffff) | ((d4.w & 255) << 16) | (b << 24);
        }
        for (; e < e1; ++e) {
            const int dv = dst[e];
            const int b = dv >> 8;
            atomicAdd(&lh[b], 1);
            stageA[e - e0] = (src[e] & 0xffff) | ((dv & 255) << 16) | (b << 24);
        }
    }
    __syncthreads();
    const int cnt_t = lh[t];
    const int inc = block_scan_incl(cnt_t, s, t);
    const int excl = inc - cnt_t;
    cur[t] = excl;
    __syncthreads();
    const int cnt = e1 - e0;
    for (int i = t; i < cnt; i += 256) {
        const int p = stageA[i];
        const int pos = atomicAdd(&cur[(int)((unsigned)p >> 24)], 1);
        stageB[pos] = p;
    }
    if (t < nbuckets) {
        int base = 0;
        if (cnt_t > 0) base = atomicAdd(&btot[t], cnt_t);
        gb[t] = t * BCAP + base - excl;
    }
    __syncthreads();
    for (int i = t; i < cnt; i += 256) {
        const int p = stageB[i];
        const int bucket = (int)((unsigned)p >> 24);
        bedge[gb[bucket] + i] = p;
    }
}

// P4': one block per bucket -> ushort csr slice, off[], dis[].
__global__ __launch_bounds__(256) void bucket_csr_kernel(
    const int* __restrict__ bedge, const int* __restrict__ btot,
    unsigned short* __restrict__ csr, int* __restrict__ off,
    float* __restrict__ dis, int N, int nbuckets)
{
    __shared__ int deg[256], cur[256], s[256];
    __shared__ int e01[2];
    __shared__ int ebuf[P4CAP];
    __shared__ unsigned short lcsr[P4CAP];
    const int t = threadIdx.x;
    const int b = blockIdx.x;

    const int bv = (t < nbuckets) ? btot[t] : 0;
    const int binc = block_scan_incl(bv, s, t);
    if (t == b) { e01[0] = binc - bv; e01[1] = binc; }
    deg[t] = 0;
    __syncthreads();
    const int e0 = e01[0], e1 = e01[1];
    const int m = e1 - e0;

    for (int i = t; i < m; i += 256) ebuf[i] = bedge[b * BCAP + i];
    __syncthreads();
    for (int i = t; i < m; i += 256)
        atomicAdd(&deg[(ebuf[i] >> 16) & 255], 1);
    __syncthreads();
    const int v = deg[t];
    const int inc = block_scan_incl(v, s, t);
    cur[t] = inc - v;
    const int node = (b << 8) + t;
    if (node < N) {
        off[node + 1] = e0 + inc;
        dis[node] = rsqrtf((float)v + 1.0f);
        if (node == 0) off[0] = 0;
    }
    __syncthreads();
    for (int i = t; i < m; i += 256) {
        const int p = ebuf[i];
        const int pos = atomicAdd(&cur[(p >> 16) & 255], 1);
        lcsr[pos] = (unsigned short)(p & 0xffff);
    }
    __syncthreads();
    for (int i = t; i < m; i += 256)
        csr[e0 + i] = lcsr[i];
}

// GEMM (layer 1): hp[i,:] = fp16((in[i,:] @ W) * dis[i]).  TR=2 tile.
template<int K, int C, int TR>
__global__ __launch_bounds__(256) void gemm_scale_kernel(
    const float* __restrict__ in, const float* __restrict__ W,
    const float* __restrict__ dis, __half* __restrict__ hp, int N)
{
    constexpr int TX = C / 4;
    constexpr int R  = (256 / TX) * TR;
    __shared__ float Wl[K * C];

    const int t = threadIdx.x;
    for (int i = t; i < K * C / 4; i += 256)
        ((float4*)Wl)[i] = ((const float4*)W)[i];
    __syncthreads();

    const int tx = t % TX, ty = t / TX;
    const int cb = tx * 4;
    const int row0 = blockIdx.x * R + ty * TR;

    float acc[TR][4];
#pragma unroll
    for (int r = 0; r < TR; ++r) acc[r][0] = acc[r][1] = acc[r][2] = acc[r][3] = 0.0f;

    auto store_row = [&](int row, int r) {
        const float d = dis[row];
        __half2 h0 = __float22half2_rn(make_float2(acc[r][0] * d, acc[r][1] * d));
        __half2 h1 = __float22half2_rn(make_float2(acc[r][2] * d, acc[r][3] * d));
        uint2 u;
        u.x = *(unsigned*)&h0;
        u.y = *(unsigned*)&h1;
        *(uint2*)&hp[(size_t)row * C + cb] = u;
    };

    if (row0 + TR <= N) {
        const float* inp = in + (size_t)row0 * K;
#pragma unroll 4
        for (int k4 = 0; k4 < K / 4; ++k4) {
            float4 w0 = *(const float4*)&Wl[(k4 * 4 + 0) * C + cb];
            float4 w1 = *(const float4*)&Wl[(k4 * 4 + 1) * C + cb];
            float4 w2 = *(const float4*)&Wl[(k4 * 4 + 2) * C + cb];
            float4 w3 = *(const float4*)&Wl[(k4 * 4 + 3) * C + cb];
#pragma unroll
            for (int r = 0; r < TR; ++r) {
                const vf4 a = __builtin_nontemporal_load((const vf4*)&inp[r * K + k4 * 4]);
                acc[r][0] = fmaf(a.x, w0.x, acc[r][0]);
                acc[r][1] = fmaf(a.x, w0.y, acc[r][1]);
                acc[r][2] = fmaf(a.x, w0.z, acc[r][2]);
                acc[r][3] = fmaf(a.x, w0.w, acc[r][3]);
                acc[r][0] = fmaf(a.y, w1.x, acc[r][0]);
                acc[r][1] = fmaf(a.y, w1.y, acc[r][1]);
                acc[r][2] = fmaf(a.y, w1.z, acc[r][2]);
                acc[r][3] = fmaf(a.y, w1.w, acc[r][3]);
                acc[r][0] = fmaf(a.z, w2.x, acc[r][0]);
                acc[r][1] = fmaf(a.z, w2.y, acc[r][1]);
                acc[r][2] = fmaf(a.z, w2.z, acc[r][2]);
                acc[r][3] = fmaf(a.z, w2.w, acc[r][3]);
                acc[r][0] = fmaf(a.w, w3.x, acc[r][0]);
                acc[r][1] = fmaf(a.w, w3.y, acc[r][1]);
                acc[r][2] = fmaf(a.w, w3.z, acc[r][2]);
                acc[r][3] = fmaf(a.w, w3.w, acc[r][3]);
            }
        }
#pragma unroll
        for (int r = 0; r < TR; ++r) store_row(row0 + r, r);
    } else {
        for (int k = 0; k < K; ++k) {
            const float4 w4 = *(const float4*)&Wl[k * C + cb];
#pragma unroll
            for (int r = 0; r < TR; ++r) {
                const int row = row0 + r;
                const float a = (row < N) ? in[(size_t)row * K + k] : 0.0f;
                acc[r][0] = fmaf(a, w4.x, acc[r][0]);
                acc[r][1] = fmaf(a, w4.y, acc[r][1]);
                acc[r][2] = fmaf(a, w4.z, acc[r][2]);
                acc[r][3] = fmaf(a, w4.w, acc[r][3]);
            }
        }
#pragma unroll
        for (int r = 0; r < TR; ++r)
            if (row0 + r < N) store_row(row0 + r, r);
    }
}

// packed-fp16 accumulate: 4 v_pk_add_f16 per 16B fragment
__device__ __forceinline__ void paccum(float4 v, __half2* a) {
    const __half2* h2 = (const __half2*)&v;
#pragma unroll
    for (int j = 0; j < 4; ++j) a[j] = __hadd2(a[j], h2[j]);
}

// Fused agg(relu,bias) + gemm_next — Wl in LDS, packed-fp16 phase A.
// NEW (R19): gather phase processes 4 nodes per wave CONCURRENTLY.
// 16 lanes per node (pair = lane>>4); each node split into 2 sub-groups of
// 8 lanes (sub = bit3) taking even/odd edges. One shfl_xor(8) reduce step.
template<int COUT, int NPB>
__global__ __launch_bounds__(256) void fused_agg_gemm_kernel(
    const int* __restrict__ off, const unsigned short* __restrict__ csr,
    const float* __restrict__ dis, const __half* __restrict__ hp_in,
    const float* __restrict__ bias, const float* __restrict__ Wn,
    __half* __restrict__ hp_out, int N)
{
    constexpr int TX  = COUT / 4;
    __shared__ float Wl[64 * COUT];
    __shared__ float Al[NPB * 65];

    const int t = threadIdx.x;
    for (int i = t; i < 64 * COUT / 4; i += 256)
        ((float4*)Wl)[i] = ((const float4*)Wn)[i];

    const int wv   = t >> 6;
    const int lane = t & 63;
    const int pair = lane >> 4;        // node within wave (0..3)
    const int sub  = (lane >> 3) & 1;  // edge half-group (even/odd)
    const int gl   = lane & 7;         // 16B slice of the 64ch row

    float b[8];
#pragma unroll
    for (int j = 0; j < 8; ++j) b[j] = bias[gl * 8 + j];

    const __half2 z2 = __float2half2_rn(0.0f);

    const int node = blockIdx.x * NPB + wv * 4 + pair;
    const int row  = wv * 4 + pair;

    __half2 acc[4]  = {z2, z2, z2, z2};
    __half2 acc2[4] = {z2, z2, z2, z2};

    if (node < N) {
        const int s0 = off[node];
        const int s1 = off[node + 1];

        if (sub == 0) {   // self-loop
            const float4 v = *(const float4*)&hp_in[(size_t)node * 64 + gl * 8];
            paccum(v, acc);
        }
        int e = s0 + sub;
        for (; e + 2 < s1; e += 4) {
            const int sa = csr[e];
            const int sb = csr[e + 2];
            const float4 va = *(const float4*)&hp_in[(size_t)sa * 64 + gl * 8];
            const float4 vb = *(const float4*)&hp_in[(size_t)sb * 64 + gl * 8];
            paccum(va, acc);
            paccum(vb, acc2);
        }
        if (e < s1) {
            const int sa = csr[e];
            const float4 va = *(const float4*)&hp_in[(size_t)sa * 64 + gl * 8];
            paccum(va, acc);
        }
#pragma unroll
        for (int j = 0; j < 4; ++j) acc[j] = __hadd2(acc[j], acc2[j]);

        // combine the two 8-lane sub-groups (lanes differing in bit 3)
#pragma unroll
        for (int j = 0; j < 4; ++j) {
            int iv = __shfl_xor(*(const int*)&acc[j], 8);
            acc[j] = __hadd2(acc[j], *(const __half2*)&iv);
        }

        if (sub == 0) {
            const float dn = dis[node];
#pragma unroll
            for (int j = 0; j < 4; ++j) {
                const float2 f = __half22float2(acc[j]);
                Al[row * 65 + gl * 8 + 2 * j]     = fmaxf(fmaf(dn, f.x, b[2 * j]), 0.0f);
                Al[row * 65 + gl * 8 + 2 * j + 1] = fmaxf(fmaf(dn, f.y, b[2 * j + 1]), 0.0f);
            }
        }
    }
    __syncthreads();

    // Phase B: Al[NPB x 64] @ Wl[64 x COUT] -> fp16 hp_out (*dis).
    // Uses TX*NPB threads (256 for COUT=64; 128 for COUT=32,NPB=16).
    const int tx = t % TX, ty = t / TX;
    if (ty < NPB) {
        const int gnode = blockIdx.x * NPB + ty;
        const int cb = tx * 4;
        float c0 = 0.f, c1 = 0.f, c2 = 0.f, c3 = 0.f;
#pragma unroll 8
        for (int k = 0; k < 64; ++k) {
            const float a = Al[ty * 65 + k];
            const float4 w4 = *(const float4*)&Wl[k * COUT + cb];
            c0 = fmaf(a, w4.x, c0);
            c1 = fmaf(a, w4.y, c1);
            c2 = fmaf(a, w4.z, c2);
            c3 = fmaf(a, w4.w, c3);
        }
        if (gnode < N) {
            const float d = dis[gnode];
            __half2 h0 = __float22half2_rn(make_float2(c0 * d, c1 * d));
            __half2 h1 = __float22half2_rn(make_float2(c2 * d, c3 * d));
            uint2 u;
            u.x = *(unsigned*)&h0;
            u.y = *(unsigned*)&h1;
            *(uint2*)&hp_out[(size_t)gnode * COUT + cb] = u;
        }
    }
}

// Final aggregation (layer 3): NEW (R19) — 4 nodes per wave concurrently,
// 16 nodes/block. 16 lanes per node: GL lanes per row slice (4 for C=32),
// SUBS=16/GL sub-groups splitting edges round-robin; log2(SUBS) shuffle steps.
template<int C, bool RELU>
__global__ __launch_bounds__(256) void agg_kernel(
    const int* __restrict__ off, const unsigned short* __restrict__ csr,
    const float* __restrict__ dis, const __half* __restrict__ hp,
    const float* __restrict__ bias, float* __restrict__ out, int N)
{
    constexpr int GL   = C / 8;       // lanes per row (4 for C=32)
    constexpr int SUBS = 16 / GL;     // sub-groups per node (4 for C=32)
    const int wv   = threadIdx.x >> 6;
    const int lane = threadIdx.x & 63;
    const int pair = lane >> 4;            // node within wave (0..3)
    const int sub  = (lane & 15) / GL;     // sub-group (0..SUBS-1)
    const int gl   = lane & (GL - 1);      // 16B slice
    const int node = blockIdx.x * 16 + wv * 4 + pair;
    if (node >= N) return;

    const int s0 = off[node];
    const int s1 = off[node + 1];

    const __half2 z2 = __float2half2_rn(0.0f);
    __half2 acc[4]  = {z2, z2, z2, z2};
    __half2 acc2[4] = {z2, z2, z2, z2};

    if (sub == 0) {   // self-loop
        const float4 v = *(const float4*)&hp[(size_t)node * C + gl * 8];
        paccum(v, acc);
    }
    int e = s0 + sub;
    for (; e + SUBS < s1; e += 2 * SUBS) {
        const int sa = csr[e];
        const int sb = csr[e + SUBS];
        const float4 va = *(const float4*)&hp[(size_t)sa * C + gl * 8];
        const float4 vb = *(const float4*)&hp[(size_t)sb * C + gl * 8];
        paccum(va, acc);
        paccum(vb, acc2);
    }
    if (e < s1) {
        const int sa = csr[e];
        const float4 va = *(const float4*)&hp[(size_t)sa * C + gl * 8];
        paccum(va, acc);
    }
#pragma unroll
    for (int j = 0; j < 4; ++j) acc[j] = __hadd2(acc[j], acc2[j]);

#pragma unroll
    for (int d = GL; d < 16; d <<= 1) {
#pragma unroll
        for (int j = 0; j < 4; ++j) {
            int iv = __shfl_xor(*(const int*)&acc[j], d);
            acc[j] = __hadd2(acc[j], *(const __half2*)&iv);
        }
    }

    if (sub == 0) {
        const float dn = dis[node];
        float v[8];
#pragma unroll
        for (int j = 0; j < 4; ++j) {
            const float2 f = __half22float2(acc[j]);
            v[2 * j]     = fmaf(dn, f.x, bias[gl * 8 + 2 * j]);
            v[2 * j + 1] = fmaf(dn, f.y, bias[gl * 8 + 2 * j + 1]);
            if (RELU) {
                v[2 * j]     = fmaxf(v[2 * j], 0.f);
                v[2 * j + 1] = fmaxf(v[2 * j + 1], 0.f);
            }
        }
        *(float4*)&out[(size_t)node * C + gl * 8]     = make_float4(v[0], v[1], v[2], v[3]);
        *(float4*)&out[(size_t)node * C + gl * 8 + 4] = make_float4(v[4], v[5], v[6], v[7]);
    }
}

static inline size_t align_up(size_t x) { return (x + 255) & ~(size_t)255; }

extern "C" void kernel_launch(void* const* d_in, const int* in_sizes, int n_in,
                              void* d_out, int out_size, void* d_ws, size_t ws_size,
                              hipStream_t stream) {
    const float* x   = (const float*)d_in[0];
    const int*  eidx = (const int*)d_in[1];
    const float* W1  = (const float*)d_in[2];
    const float* b1  = (const float*)d_in[3];
    const float* W2  = (const float*)d_in[4];
    const float* b2  = (const float*)d_in[5];
    const float* W3  = (const float*)d_in[6];
    const float* b3  = (const float*)d_in[7];
    float* out = (float*)d_out;

    const int N = in_sizes[0] / 128;   // 50000 (< 65536 required for packing)
    const int E = in_sizes[1] / 2;     // 800000
    const int* srcp = eidx;
    const int* dstp = eidx + E;
    const int nbuckets = (N + 255) >> 8;   // 196

    char* ws = (char*)d_ws;
    size_t o = 0;
    float* dis          = (float*)(ws + o);          o = align_up(o + (size_t)N * 4);
    int* off            = (int*)(ws + o);            o = align_up(o + (size_t)(N + 1) * 4);
    int* btot           = (int*)(ws + o);            o = align_up(o + 256 * 4);
    int* bedge          = (int*)(ws + o);            o = align_up(o + (size_t)nbuckets * BCAP * 4);
    unsigned short* csr = (unsigned short*)(ws + o); o = align_up(o + (size_t)E * 2);
    __half* H1          = (__half*)(ws + o);         o = align_up(o + (size_t)N * 64 * 2);
    __half* H2          = (__half*)(ws + o);         o = align_up(o + (size_t)N * 64 * 2);
    __half* H3          = H1;   // H1 dead after fused2 completes (separate dispatch)

    const dim3 blk(256);

    // --- CSR build: zero counters, single-pass sort+reserve, per-bucket csr ---
    hipMemsetAsync(btot, 0, 256 * sizeof(int), stream);
    part_sort_reserve_kernel<<<dim3(256), blk, 0, stream>>>(srcp, dstp, btot, bedge, E, nbuckets);
    bucket_csr_kernel<<<dim3(nbuckets), blk, 0, stream>>>(bedge, btot, csr, off, dis, N, nbuckets);

    // --- layer 1 GEMM: x[128] @ W1 -> H1 (fp16, *dis) ---
    gemm_scale_kernel<128, 64, 2><<<dim3((N + 31) / 32), blk, 0, stream>>>(x, W1, dis, H1, N);

    // --- fused agg1(relu,b1) + gemm2 -> H2 (fp16, *dis) ---
    fused_agg_gemm_kernel<64, 16><<<dim3((N + 15) / 16), blk, 0, stream>>>(
        off, csr, dis, H1, b1, W2, H2, N);
    // --- fused agg2(relu,b2) + gemm3 -> H3 (fp16 32-ch, *dis) ---
    fused_agg_gemm_kernel<32, 16><<<dim3((N + 15) / 16), blk, 0, stream>>>(
        off, csr, dis, H2, b2, W3, H3, N);
    // --- final agg3 (+b3, no relu) -> out (fp32) ---
    agg_kernel<32, false><<<dim3((N + 15) / 16), blk, 0, stream>>>(off, csr, dis, H3, b3, out, N);
}

// Round 2
// 175.648 us; speedup vs baseline: 1.1520x; 1.0295x over previous
//
#include <hip/hip_runtime.h>
#include <hip/hip_fp16.h>

// ---------------------------------------------------------------------------
// BasketballGNN round 20: R19 + LDS-staged csr slices in the gather kernels.
// Theory: gather edge-loops carry a serialized csr[e] global-load -> gather
// address dependency (~200cy/iter). Block's edge slice is contiguous (~256
// entries); stage it into LDS once (coalesced), then index reads are ds_read
// (~20cy) and gathers pipeline freely. Also unroll gather 4 edges/iter.
// Everything else identical to R19 (180.8us).
// ---------------------------------------------------------------------------

#define P3CAP 3200   // >= chunk (3128 for E=800k)
#define P4CAP 8192   // >= max edges per 256-node bucket (mean 4082, +64 sigma)
#define BCAP  8192   // per-bucket region stride in bedge
#define CSRCAP 768   // >= max edges per 16-node block (mean 256, +32 sigma)

typedef float vf4 __attribute__((ext_vector_type(4)));

__device__ __forceinline__ int block_scan_incl(int v, int* s, int t) {
    s[t] = v;
    __syncthreads();
#pragma unroll
    for (int d = 1; d < 256; d <<= 1) {
        int a = (t >= d) ? s[t - d] : 0;
        __syncthreads();
        s[t] += a;
        __syncthreads();
    }
    return s[t];
}

__host__ __device__ __forceinline__ int chunk_of(int E) {
    return (((E + 255) / 256) + 3) & ~3;
}

// P3' single-pass: stage packed edges in arrival order while counting, LDS
// counting-sort into bucket-grouped order, atomic run reservation, flush.
__global__ __launch_bounds__(256) void part_sort_reserve_kernel(
    const int* __restrict__ src, const int* __restrict__ dst,
    int* __restrict__ btot, int* __restrict__ bedge, int E, int nbuckets)
{
    __shared__ int lh[256], gb[256], cur[256], s[256];
    __shared__ int stageA[P3CAP];
    __shared__ int stageB[P3CAP];
    const int t = threadIdx.x;

    lh[t] = 0;
    __syncthreads();
    const int chunk = chunk_of(E);
    const int e0 = blockIdx.x * chunk;
    const int e1 = min(E, e0 + chunk);
    {
        int e = e0 + t * 4;
        for (; e + 3 < e1; e += 1024) {
            const int4 d4 = *(const int4*)&dst[e];
            const int4 s4 = *(const int4*)&src[e];
            const int i = e - e0;
            int b;
            b = d4.x >> 8; atomicAdd(&lh[b], 1);
            stageA[i]     = (s4.x & 0xffff) | ((d4.x & 255) << 16) | (b << 24);
            b = d4.y >> 8; atomicAdd(&lh[b], 1);
            stageA[i + 1] = (s4.y & 0xffff) | ((d4.y & 255) << 16) | (b << 24);
            b = d4.z >> 8; atomicAdd(&lh[b], 1);
            stageA[i + 2] = (s4.z & 0xffff) | ((d4.z & 255) << 16) | (b << 24);
            b = d4.w >> 8; atomicAdd(&lh[b], 1);
            stageA[i + 3] = (s4.w & 0xffff) | ((d4.w & 255) << 16) | (b << 24);
        }
        for (; e < e1; ++e) {
            const int dv = dst[e];
            const int b = dv >> 8;
            atomicAdd(&lh[b], 1);
            stageA[e - e0] = (src[e] & 0xffff) | ((dv & 255) << 16) | (b << 24);
        }
    }
    __syncthreads();
    const int cnt_t = lh[t];
    const int inc = block_scan_incl(cnt_t, s, t);
    const int excl = inc - cnt_t;
    cur[t] = excl;
    __syncthreads();
    const int cnt = e1 - e0;
    for (int i = t; i < cnt; i += 256) {
        const int p = stageA[i];
        const int pos = atomicAdd(&cur[(int)((unsigned)p >> 24)], 1);
        stageB[pos] = p;
    }
    if (t < nbuckets) {
        int base = 0;
        if (cnt_t > 0) base = atomicAdd(&btot[t], cnt_t);
        gb[t] = t * BCAP + base - excl;
    }
    __syncthreads();
    for (int i = t; i < cnt; i += 256) {
        const int p = stageB[i];
        const int bucket = (int)((unsigned)p >> 24);
        bedge[gb[bucket] + i] = p;
    }
}

// P4': one block per bucket -> ushort csr slice, off[], dis[].
__global__ __launch_bounds__(256) void bucket_csr_kernel(
    const int* __restrict__ bedge, const int* __restrict__ btot,
    unsigned short* __restrict__ csr, int* __restrict__ off,
    float* __restrict__ dis, int N, int nbuckets)
{
    __shared__ int deg[256], cur[256], s[256];
    __shared__ int e01[2];
    __shared__ int ebuf[P4CAP];
    __shared__ unsigned short lcsr[P4CAP];
    const int t = threadIdx.x;
    const int b = blockIdx.x;

    const int bv = (t < nbuckets) ? btot[t] : 0;
    const int binc = block_scan_incl(bv, s, t);
    if (t == b) { e01[0] = binc - bv; e01[1] = binc; }
    deg[t] = 0;
    __syncthreads();
    const int e0 = e01[0], e1 = e01[1];
    const int m = e1 - e0;

    for (int i = t; i < m; i += 256) ebuf[i] = bedge[b * BCAP + i];
    __syncthreads();
    for (int i = t; i < m; i += 256)
        atomicAdd(&deg[(ebuf[i] >> 16) & 255], 1);
    __syncthreads();
    const int v = deg[t];
    const int inc = block_scan_incl(v, s, t);
    cur[t] = inc - v;
    const int node = (b << 8) + t;
    if (node < N) {
        off[node + 1] = e0 + inc;
        dis[node] = rsqrtf((float)v + 1.0f);
        if (node == 0) off[0] = 0;
    }
    __syncthreads();
    for (int i = t; i < m; i += 256) {
        const int p = ebuf[i];
        const int pos = atomicAdd(&cur[(p >> 16) & 255], 1);
        lcsr[pos] = (unsigned short)(p & 0xffff);
    }
    __syncthreads();
    for (int i = t; i < m; i += 256)
        csr[e0 + i] = lcsr[i];
}

// GEMM (layer 1): hp[i,:] = fp16((in[i,:] @ W) * dis[i]).  TR=2 tile.
template<int K, int C, int TR>
__global__ __launch_bounds__(256) void gemm_scale_kernel(
    const float* __restrict__ in, const float* __restrict__ W,
    const float* __restrict__ dis, __half* __restrict__ hp, int N)
{
    constexpr int TX = C / 4;
    constexpr int R  = (256 / TX) * TR;
    __shared__ float Wl[K * C];

    const int t = threadIdx.x;
    for (int i = t; i < K * C / 4; i += 256)
        ((float4*)Wl)[i] = ((const float4*)W)[i];
    __syncthreads();

    const int tx = t % TX, ty = t / TX;
    const int cb = tx * 4;
    const int row0 = blockIdx.x * R + ty * TR;

    float acc[TR][4];
#pragma unroll
    for (int r = 0; r < TR; ++r) acc[r][0] = acc[r][1] = acc[r][2] = acc[r][3] = 0.0f;

    auto store_row = [&](int row, int r) {
        const float d = dis[row];
        __half2 h0 = __float22half2_rn(make_float2(acc[r][0] * d, acc[r][1] * d));
        __half2 h1 = __float22half2_rn(make_float2(acc[r][2] * d, acc[r][3] * d));
        uint2 u;
        u.x = *(unsigned*)&h0;
        u.y = *(unsigned*)&h1;
        *(uint2*)&hp[(size_t)row * C + cb] = u;
    };

    if (row0 + TR <= N) {
        const float* inp = in + (size_t)row0 * K;
#pragma unroll 4
        for (int k4 = 0; k4 < K / 4; ++k4) {
            float4 w0 = *(const float4*)&Wl[(k4 * 4 + 0) * C + cb];
            float4 w1 = *(const float4*)&Wl[(k4 * 4 + 1) * C + cb];
            float4 w2 = *(const float4*)&Wl[(k4 * 4 + 2) * C + cb];
            float4 w3 = *(const float4*)&Wl[(k4 * 4 + 3) * C + cb];
#pragma unroll
            for (int r = 0; r < TR; ++r) {
                const vf4 a = __builtin_nontemporal_load((const vf4*)&inp[r * K + k4 * 4]);
                acc[r][0] = fmaf(a.x, w0.x, acc[r][0]);
                acc[r][1] = fmaf(a.x, w0.y, acc[r][1]);
                acc[r][2] = fmaf(a.x, w0.z, acc[r][2]);
                acc[r][3] = fmaf(a.x, w0.w, acc[r][3]);
                acc[r][0] = fmaf(a.y, w1.x, acc[r][0]);
                acc[r][1] = fmaf(a.y, w1.y, acc[r][1]);
                acc[r][2] = fmaf(a.y, w1.z, acc[r][2]);
                acc[r][3] = fmaf(a.y, w1.w, acc[r][3]);
                acc[r][0] = fmaf(a.z, w2.x, acc[r][0]);
                acc[r][1] = fmaf(a.z, w2.y, acc[r][1]);
                acc[r][2] = fmaf(a.z, w2.z, acc[r][2]);
                acc[r][3] = fmaf(a.z, w2.w, acc[r][3]);
                acc[r][0] = fmaf(a.w, w3.x, acc[r][0]);
                acc[r][1] = fmaf(a.w, w3.y, acc[r][1]);
                acc[r][2] = fmaf(a.w, w3.z, acc[r][2]);
                acc[r][3] = fmaf(a.w, w3.w, acc[r][3]);
            }
        }
#pragma unroll
        for (int r = 0; r < TR; ++r) store_row(row0 + r, r);
    } else {
        for (int k = 0; k < K; ++k) {
            const float4 w4 = *(const float4*)&Wl[k * C + cb];
#pragma unroll
            for (int r = 0; r < TR; ++r) {
                const int row = row0 + r;
                const float a = (row < N) ? in[(size_t)row * K + k] : 0.0f;
                acc[r][0] = fmaf(a, w4.x, acc[r][0]);
                acc[r][1] = fmaf(a, w4.y, acc[r][1]);
                acc[r][2] = fmaf(a, w4.z, acc[r][2]);
                acc[r][3] = fmaf(a, w4.w, acc[r][3]);
            }
        }
#pragma unroll
        for (int r = 0; r < TR; ++r)
            if (row0 + r < N) store_row(row0 + r, r);
    }
}

// packed-fp16 accumulate: 4 v_pk_add_f16 per 16B fragment
__device__ __forceinline__ void paccum(float4 v, __half2* a) {
    const __half2* h2 = (const __half2*)&v;
#pragma unroll
    for (int j = 0; j < 4; ++j) a[j] = __hadd2(a[j], h2[j]);
}

// Fused agg(relu,bias) + gemm_next — Wl in LDS, packed-fp16 phase A.
// R19: 4 nodes per wave concurrently (16 lanes/node, 2 sub-groups of 8).
// R20: block's contiguous csr slice staged in LDS; 4-edge unrolled gather.
template<int COUT, int NPB>
__global__ __launch_bounds__(256) void fused_agg_gemm_kernel(
    const int* __restrict__ off, const unsigned short* __restrict__ csr,
    const float* __restrict__ dis, const __half* __restrict__ hp_in,
    const float* __restrict__ bias, const float* __restrict__ Wn,
    __half* __restrict__ hp_out, int N)
{
    constexpr int TX  = COUT / 4;
    __shared__ float Wl[64 * COUT];
    __shared__ float Al[NPB * 65];
    __shared__ unsigned short csr_l[CSRCAP];

    const int t = threadIdx.x;
    for (int i = t; i < 64 * COUT / 4; i += 256)
        ((float4*)Wl)[i] = ((const float4*)Wn)[i];

    // stage this block's contiguous csr slice into LDS
    const int nb0 = blockIdx.x * NPB;
    const int nb1 = min(nb0 + NPB, N);
    const int eb0 = off[nb0];
    const int mblk = off[nb1] - eb0;
    const bool use_lds = (mblk <= CSRCAP);
    if (use_lds) {
        for (int i = t; i < mblk; i += 256) csr_l[i] = csr[eb0 + i];
    }

    const int wv   = t >> 6;
    const int lane = t & 63;
    const int pair = lane >> 4;        // node within wave (0..3)
    const int sub  = (lane >> 3) & 1;  // edge half-group (even/odd)
    const int gl   = lane & 7;         // 16B slice of the 64ch row

    float b[8];
#pragma unroll
    for (int j = 0; j < 8; ++j) b[j] = bias[gl * 8 + j];

    const __half2 z2 = __float2half2_rn(0.0f);

    const int node = nb0 + wv * 4 + pair;
    const int row  = wv * 4 + pair;

    __half2 acc[4]  = {z2, z2, z2, z2};
    __half2 acc2[4] = {z2, z2, z2, z2};

    __syncthreads();   // csr_l (and Wl) visible

    if (node < N) {
        const int s0 = off[node];
        const int s1 = off[node + 1];

        if (sub == 0) {   // self-loop
            const float4 v = *(const float4*)&hp_in[(size_t)node * 64 + gl * 8];
            paccum(v, acc);
        }

        auto run_gather = [&](auto IDX) {
            int e = s0 + sub;
            for (; e + 6 < s1; e += 8) {
                const int sa = IDX(e);
                const int sb = IDX(e + 2);
                const int sc = IDX(e + 4);
                const int sd = IDX(e + 6);
                const float4 va = *(const float4*)&hp_in[(size_t)sa * 64 + gl * 8];
                const float4 vb = *(const float4*)&hp_in[(size_t)sb * 64 + gl * 8];
                const float4 vc = *(const float4*)&hp_in[(size_t)sc * 64 + gl * 8];
                const float4 vd = *(const float4*)&hp_in[(size_t)sd * 64 + gl * 8];
                paccum(va, acc);
                paccum(vb, acc2);
                paccum(vc, acc);
                paccum(vd, acc2);
            }
            for (; e + 2 < s1; e += 4) {
                const int sa = IDX(e);
                const int sb = IDX(e + 2);
                const float4 va = *(const float4*)&hp_in[(size_t)sa * 64 + gl * 8];
                const float4 vb = *(const float4*)&hp_in[(size_t)sb * 64 + gl * 8];
                paccum(va, acc);
                paccum(vb, acc2);
            }
            if (e < s1) {
                const int sa = IDX(e);
                const float4 va = *(const float4*)&hp_in[(size_t)sa * 64 + gl * 8];
                paccum(va, acc);
            }
        };
        if (use_lds) run_gather([&](int e) { return (int)csr_l[e - eb0]; });
        else         run_gather([&](int e) { return (int)csr[e]; });

#pragma unroll
        for (int j = 0; j < 4; ++j) acc[j] = __hadd2(acc[j], acc2[j]);

        // combine the two 8-lane sub-groups (lanes differing in bit 3)
#pragma unroll
        for (int j = 0; j < 4; ++j) {
            int iv = __shfl_xor(*(const int*)&acc[j], 8);
            acc[j] = __hadd2(acc[j], *(const __half2*)&iv);
        }

        if (sub == 0) {
            const float dn = dis[node];
#pragma unroll
            for (int j = 0; j < 4; ++j) {
                const float2 f = __half22float2(acc[j]);
                Al[row * 65 + gl * 8 + 2 * j]     = fmaxf(fmaf(dn, f.x, b[2 * j]), 0.0f);
                Al[row * 65 + gl * 8 + 2 * j + 1] = fmaxf(fmaf(dn, f.y, b[2 * j + 1]), 0.0f);
            }
        }
    }
    __syncthreads();

    // Phase B: Al[NPB x 64] @ Wl[64 x COUT] -> fp16 hp_out (*dis).
    // Uses TX*NPB threads (256 for COUT=64; 128 for COUT=32,NPB=16).
    const int tx = t % TX, ty = t / TX;
    if (ty < NPB) {
        const int gnode = blockIdx.x * NPB + ty;
        const int cb = tx * 4;
        float c0 = 0.f, c1 = 0.f, c2 = 0.f, c3 = 0.f;
#pragma unroll 8
        for (int k = 0; k < 64; ++k) {
            const float a = Al[ty * 65 + k];
            const float4 w4 = *(const float4*)&Wl[k * COUT + cb];
            c0 = fmaf(a, w4.x, c0);
            c1 = fmaf(a, w4.y, c1);
            c2 = fmaf(a, w4.z, c2);
            c3 = fmaf(a, w4.w, c3);
        }
        if (gnode < N) {
            const float d = dis[gnode];
            __half2 h0 = __float22half2_rn(make_float2(c0 * d, c1 * d));
            __half2 h1 = __float22half2_rn(make_float2(c2 * d, c3 * d));
            uint2 u;
            u.x = *(unsigned*)&h0;
            u.y = *(unsigned*)&h1;
            *(uint2*)&hp_out[(size_t)gnode * COUT + cb] = u;
        }
    }
}

// Final aggregation (layer 3): 4 nodes per wave concurrently, 16 nodes/block.
// R20: block's csr slice staged in LDS; 4-edge unrolled gather.
template<int C, bool RELU>
__global__ __launch_bounds__(256) void agg_kernel(
    const int* __restrict__ off, const unsigned short* __restrict__ csr,
    const float* __restrict__ dis, const __half* __restrict__ hp,
    const float* __restrict__ bias, float* __restrict__ out, int N)
{
    constexpr int GL   = C / 8;       // lanes per row (4 for C=32)
    constexpr int SUBS = 16 / GL;     // sub-groups per node (4 for C=32)
    __shared__ unsigned short csr_l[CSRCAP];

    const int nb0 = blockIdx.x * 16;
    const int nb1 = min(nb0 + 16, N);
    const int eb0 = off[nb0];
    const int mblk = off[nb1] - eb0;
    const bool use_lds = (mblk <= CSRCAP);
    if (use_lds) {
        for (int i = threadIdx.x; i < mblk; i += 256) csr_l[i] = csr[eb0 + i];
    }
    __syncthreads();

    const int wv   = threadIdx.x >> 6;
    const int lane = threadIdx.x & 63;
    const int pair = lane >> 4;            // node within wave (0..3)
    const int sub  = (lane & 15) / GL;     // sub-group (0..SUBS-1)
    const int gl   = lane & (GL - 1);      // 16B slice
    const int node = nb0 + wv * 4 + pair;
    if (node >= N) return;

    const int s0 = off[node];
    const int s1 = off[node + 1];

    const __half2 z2 = __float2half2_rn(0.0f);
    __half2 acc[4]  = {z2, z2, z2, z2};
    __half2 acc2[4] = {z2, z2, z2, z2};

    if (sub == 0) {   // self-loop
        const float4 v = *(const float4*)&hp[(size_t)node * C + gl * 8];
        paccum(v, acc);
    }

    auto run_gather = [&](auto IDX) {
        int e = s0 + sub;
        for (; e + 3 * SUBS < s1; e += 4 * SUBS) {
            const int sa = IDX(e);
            const int sb = IDX(e + SUBS);
            const int sc = IDX(e + 2 * SUBS);
            const int sd = IDX(e + 3 * SUBS);
            const float4 va = *(const float4*)&hp[(size_t)sa * C + gl * 8];
            const float4 vb = *(const float4*)&hp[(size_t)sb * C + gl * 8];
            const float4 vc = *(const float4*)&hp[(size_t)sc * C + gl * 8];
            const float4 vd = *(const float4*)&hp[(size_t)sd * C + gl * 8];
            paccum(va, acc);
            paccum(vb, acc2);
            paccum(vc, acc);
            paccum(vd, acc2);
        }
        for (; e + SUBS < s1; e += 2 * SUBS) {
            const int sa = IDX(e);
            const int sb = IDX(e + SUBS);
            const float4 va = *(const float4*)&hp[(size_t)sa * C + gl * 8];
            const float4 vb = *(const float4*)&hp[(size_t)sb * C + gl * 8];
            paccum(va, acc);
            paccum(vb, acc2);
        }
        if (e < s1) {
            const int sa = IDX(e);
            const float4 va = *(const float4*)&hp[(size_t)sa * C + gl * 8];
            paccum(va, acc);
        }
    };
    if (use_lds) run_gather([&](int e) { return (int)csr_l[e - eb0]; });
    else         run_gather([&](int e) { return (int)csr[e]; });

#pragma unroll
    for (int j = 0; j < 4; ++j) acc[j] = __hadd2(acc[j], acc2[j]);

#pragma unroll
    for (int d = GL; d < 16; d <<= 1) {
#pragma unroll
        for (int j = 0; j < 4; ++j) {
            int iv = __shfl_xor(*(const int*)&acc[j], d);
            acc[j] = __hadd2(acc[j], *(const __half2*)&iv);
        }
    }

    if (sub == 0) {
        const float dn = dis[node];
        float v[8];
#pragma unroll
        for (int j = 0; j < 4; ++j) {
            const float2 f = __half22float2(acc[j]);
            v[2 * j]     = fmaf(dn, f.x, bias[gl * 8 + 2 * j]);
            v[2 * j + 1] = fmaf(dn, f.y, bias[gl * 8 + 2 * j + 1]);
            if (RELU) {
                v[2 * j]     = fmaxf(v[2 * j], 0.f);
                v[2 * j + 1] = fmaxf(v[2 * j + 1], 0.f);
            }
        }
        *(float4*)&out[(size_t)node * C + gl * 8]     = make_float4(v[0], v[1], v[2], v[3]);
        *(float4*)&out[(size_t)node * C + gl * 8 + 4] = make_float4(v[4], v[5], v[6], v[7]);
    }
}

static inline size_t align_up(size_t x) { return (x + 255) & ~(size_t)255; }

extern "C" void kernel_launch(void* const* d_in, const int* in_sizes, int n_in,
                              void* d_out, int out_size, void* d_ws, size_t ws_size,
                              hipStream_t stream) {
    const float* x   = (const float*)d_in[0];
    const int*  eidx = (const int*)d_in[1];
    const float* W1  = (const float*)d_in[2];
    const float* b1  = (const float*)d_in[3];
    const float* W2  = (const float*)d_in[4];
    const float* b2  = (const float*)d_in[5];
    const float* W3  = (const float*)d_in[6];
    const float* b3  = (const float*)d_in[7];
    float* out = (float*)d_out;

    const int N = in_sizes[0] / 128;   // 50000 (< 65536 required for packing)
    const int E = in_sizes[1] / 2;     // 800000
    const int* srcp = eidx;
    const int* dstp = eidx + E;
    const int nbuckets = (N + 255) >> 8;   // 196

    char* ws = (char*)d_ws;
    size_t o = 0;
    float* dis          = (float*)(ws + o);          o = align_up(o + (size_t)N * 4);
    int* off            = (int*)(ws + o);            o = align_up(o + (size_t)(N + 1) * 4);
    int* btot           = (int*)(ws + o);            o = align_up(o + 256 * 4);
    int* bedge          = (int*)(ws + o);            o = align_up(o + (size_t)nbuckets * BCAP * 4);
    unsigned short* csr = (unsigned short*)(ws + o); o = align_up(o + (size_t)E * 2);
    __half* H1          = (__half*)(ws + o);         o = align_up(o + (size_t)N * 64 * 2);
    __half* H2          = (__half*)(ws + o);         o = align_up(o + (size_t)N * 64 * 2);
    __half* H3          = H1;   // H1 dead after fused2 completes (separate dispatch)

    const dim3 blk(256);

    // --- CSR build: zero counters, single-pass sort+reserve, per-bucket csr ---
    hipMemsetAsync(btot, 0, 256 * sizeof(int), stream);
    part_sort_reserve_kernel<<<dim3(256), blk, 0, stream>>>(srcp, dstp, btot, bedge, E, nbuckets);
    bucket_csr_kernel<<<dim3(nbuckets), blk, 0, stream>>>(bedge, btot, csr, off, dis, N, nbuckets);

    // --- layer 1 GEMM: x[128] @ W1 -> H1 (fp16, *dis) ---
    gemm_scale_kernel<128, 64, 2><<<dim3((N + 31) / 32), blk, 0, stream>>>(x, W1, dis, H1, N);

    // --- fused agg1(relu,b1) + gemm2 -> H2 (fp16, *dis) ---
    fused_agg_gemm_kernel<64, 16><<<dim3((N + 15) / 16), blk, 0, stream>>>(
        off, csr, dis, H1, b1, W2, H2, N);
    // --- fused agg2(relu,b2) + gemm3 -> H3 (fp16 32-ch, *dis) ---
    fused_agg_gemm_kernel<32, 16><<<dim3((N + 15) / 16), blk, 0, stream>>>(
        off, csr, dis, H2, b2, W3, H3, N);
    // --- final agg3 (+b3, no relu) -> out (fp32) ---
    agg_kernel<32, false><<<dim3((N + 15) / 16), blk, 0, stream>>>(off, csr, dis, H3, b3, out, N);
}